// Round 6
// baseline (285.236 us; speedup 1.0000x reference)
//
#include <hip/hip_runtime.h>
#include <stdint.h>

#define Bdim 512
#define Tdim 2000
#define Ddim 20
#define Hdim 128
#define Cdim 10
#define GS 16                    // steps per load-group: 16*20 = 320 floats = 5 dword/lane
#define NGRP 125                 // 125 * 16 = 2000 exactly (no tail, no clamp)
#define BETA 0.95f
#define THR 0.8f

typedef float f32x2 __attribute__((ext_vector_type(2)));
typedef int   i32x2 __attribute__((ext_vector_type(2)));

// x broadcast: value was loaded per-lane (coalesced); readlane moves it to SGPR.
#define RL(BUF, F) __builtin_amdgcn_readlane(BUF[(F) >> 6], (F) & 63)

// packed fp32 with scalar x-pair operand (1 const-bus read: legal)
#define PKMUL(ACC, XP, WP) asm("v_pk_mul_f32 %0, %1, %2"     : "=v"(ACC) : "s"(XP), "v"(WP))
#define PKFMA(ACC, XP, WP) asm("v_pk_fma_f32 %0, %1, %2, %0" : "+v"(ACC) : "s"(XP), "v"(WP))
#define PKADD(ACC, A_, B_) asm("v_pk_add_f32 %0, %1, %2"     : "=v"(ACC) : "v"(A_), "v"(B_))

__global__ __launch_bounds__(128, 1) void snn_fused_kernel(
    const float* __restrict__ x,   // [B,T,D]
    const float* __restrict__ W1,  // [H,D]
    const float* __restrict__ b1,  // [H]
    const float* __restrict__ W2,  // [C,H]
    const float* __restrict__ b2,  // [C]
    float* __restrict__ out)       // [B,C]
{
    const int b    = blockIdx.x;
    const int tid  = threadIdx.x;   // 0..127: head index
    const int lane = tid & 63;

    __shared__ float cnt_s[Hdim];

    // W1 row for this head as 10 f32x2 pairs (rows are 80 B, 8-B aligned)
    f32x2 wv[10];
    {
        const f32x2* wr = (const f32x2*)(W1 + tid * Ddim);
#pragma unroll
        for (int j = 0; j < 10; ++j) wv[j] = wr[j];
    }
    const float bias  = b1[tid];
    const float biasm = bias - THR;

    const float* xb = x + (size_t)b * Tdim * Ddim;

    // 5 coalesced dword loads per group (asm-pinned so they cannot sink)
    int bufA[5], bufB[5];
#define ISSUE5(BUF, G)  {                                                                   \
        _Pragma("unroll")                                                                   \
        for (int c_ = 0; c_ < 5; ++c_) {                                                    \
            const float* p_ = xb + (G) * (GS * Ddim) + c_ * 64 + lane;                      \
            asm volatile("global_load_dword %0, %1, off" : "=v"(BUF[c_]) : "v"(p_));        \
        }                                                                                   \
    }

    float    mem  = 0.0f;
    unsigned cnt  = 0u;
    float    addB = bias;           // bias - THR*spike(prev)

#define STEP(BUF, S) {                                                                      \
        i32x2 xp0, xp1, xp2, xp3, xp4, xp5, xp6, xp7, xp8, xp9;                             \
        xp0[0] = RL(BUF,(S)*20+ 0); xp0[1] = RL(BUF,(S)*20+ 1);                             \
        xp1[0] = RL(BUF,(S)*20+ 2); xp1[1] = RL(BUF,(S)*20+ 3);                             \
        xp2[0] = RL(BUF,(S)*20+ 4); xp2[1] = RL(BUF,(S)*20+ 5);                             \
        xp3[0] = RL(BUF,(S)*20+ 6); xp3[1] = RL(BUF,(S)*20+ 7);                             \
        xp4[0] = RL(BUF,(S)*20+ 8); xp4[1] = RL(BUF,(S)*20+ 9);                             \
        xp5[0] = RL(BUF,(S)*20+10); xp5[1] = RL(BUF,(S)*20+11);                             \
        xp6[0] = RL(BUF,(S)*20+12); xp6[1] = RL(BUF,(S)*20+13);                             \
        xp7[0] = RL(BUF,(S)*20+14); xp7[1] = RL(BUF,(S)*20+15);                             \
        xp8[0] = RL(BUF,(S)*20+16); xp8[1] = RL(BUF,(S)*20+17);                             \
        xp9[0] = RL(BUF,(S)*20+18); xp9[1] = RL(BUF,(S)*20+19);                             \
        f32x2 a0, a1;                                                                       \
        PKMUL(a0, xp0, wv[0]); PKMUL(a1, xp1, wv[1]);                                       \
        PKFMA(a0, xp2, wv[2]); PKFMA(a1, xp3, wv[3]);                                       \
        PKFMA(a0, xp4, wv[4]); PKFMA(a1, xp5, wv[5]);                                       \
        PKFMA(a0, xp6, wv[6]); PKFMA(a1, xp7, wv[7]);                                       \
        PKFMA(a0, xp8, wv[8]); PKFMA(a1, xp9, wv[9]);                                       \
        f32x2 asum; PKADD(asum, a0, a1);                                                    \
        const float dot = asum[0] + asum[1];                                                \
        mem = fmaf(BETA, mem, dot) + addB;                                                  \
        const bool sp = mem > THR;                                                          \
        cnt += sp ? 1u : 0u;                                                                \
        addB = sp ? biasm : bias;                                                           \
    }

#define ST4(BUF, S)  STEP(BUF, S) STEP(BUF, (S)+1) STEP(BUF, (S)+2) STEP(BUF, (S)+3)
#define ST16(BUF)    ST4(BUF, 0) ST4(BUF, 4) ST4(BUF, 8) ST4(BUF, 12)

#define VMWAIT0()  asm volatile("s_waitcnt vmcnt(0)" ::: "memory"); \
                   __builtin_amdgcn_sched_barrier(0);

    // prologue
    ISSUE5(bufA, 0);
    VMWAIT0();

    // groups 0..123 in (A,B) pairs; each body prefetches the next group
    for (int i = 0; i < 62; ++i) {
        const int g = 2 * i;
        ISSUE5(bufB, g + 1);
        ST16(bufA)
        VMWAIT0();
        ISSUE5(bufA, g + 2);   // for i=61 this is group 124 (the last)
        ST16(bufB)
        VMWAIT0();
    }
    // final group 124 (already loaded into bufA, already waited)
    ST16(bufA)

#undef STEP
#undef ST4
#undef ST16

    // epilogue: logits[b,:] from this block's 128 spike counts
    cnt_s[tid] = (float)cnt;
    __syncthreads();
    if (tid < Cdim) {
        float dot = 0.0f;
#pragma unroll
        for (int k = 0; k < Hdim; ++k)
            dot = fmaf(cnt_s[k], W2[tid * Hdim + k], dot);
        const float Tf = (float)Tdim;
        const float scale = 1.0f / Tf + 0.1f / (Tf + 1e-6f);
        out[b * Cdim + tid] = fmaf(dot, scale, 1.1f * b2[tid]);
    }
}

extern "C" void kernel_launch(void* const* d_in, const int* in_sizes, int n_in,
                              void* d_out, int out_size, void* d_ws, size_t ws_size,
                              hipStream_t stream) {
    const float* x  = (const float*)d_in[0];
    const float* W1 = (const float*)d_in[1];
    const float* b1 = (const float*)d_in[2];
    const float* W2 = (const float*)d_in[3];
    const float* b2 = (const float*)d_in[4];
    float* out = (float*)d_out;

    snn_fused_kernel<<<dim3(Bdim), dim3(128), 0, stream>>>(x, W1, b1, W2, b2, out);
}

// Round 7
// 271.773 us; speedup vs baseline: 1.0495x; 1.0495x over previous
//
#include <hip/hip_runtime.h>
#include <stdint.h>

#define Bdim 512
#define Tdim 2000
#define Ddim 20
#define Hdim 128
#define Cdim 10
#define TB 128
#define TBP (TB + 4)     // pad: phantom group reads reach rows nt..nt+1
#define NTILES 16        // 15*128 + 80
#define BETA 0.95f
#define THR 0.8f

typedef float f32x2 __attribute__((ext_vector_type(2)));
typedef float f32x4 __attribute__((ext_vector_type(4)));

#define PKMUL(ACC, XP, WP) asm("v_pk_mul_f32 %0, %1, %2"     : "=v"(ACC) : "v"(XP), "v"(WP))
#define PKFMA(ACC, XP, WP) asm("v_pk_fma_f32 %0, %1, %2, %0" : "+v"(ACC) : "v"(XP), "v"(WP))
#define PKADD(ACC, A_, B_) asm("v_pk_add_f32 %0, %1, %2"     : "=v"(ACC) : "v"(A_), "v"(B_))

template<int N> struct ICst { static constexpr int v = N; };

__global__ __launch_bounds__(64, 1) void snn_fused_kernel(
    const float* __restrict__ x,   // [B,T,D]
    const float* __restrict__ W1,  // [H,D]
    const float* __restrict__ b1,  // [H]
    const float* __restrict__ W2,  // [C,H]
    const float* __restrict__ b2,  // [C]
    float* __restrict__ out)       // [B,C]
{
    const int b    = blockIdx.x;
    const int lane = threadIdx.x;  // 0..63

    __shared__ __align__(16) float xs[2][TBP * Ddim];   // 2 x 10560 B
    __shared__ float cnt_s[Hdim];

    // W1 rows for head0 = lane, head1 = lane+64, as f32x2 pairs over d
    f32x2 wA[10], wB[10];
    {
        const f32x2* rA = (const f32x2*)(W1 + lane * Ddim);
        const f32x2* rB = (const f32x2*)(W1 + (lane + 64) * Ddim);
#pragma unroll
        for (int p = 0; p < 10; ++p) { wA[p] = rA[p]; wB[p] = rB[p]; }
    }
    const float biasA  = b1[lane];
    const float biasB  = b1[lane + 64];
    const float biasAm = biasA - THR;
    const float biasBm = biasB - THR;

    const float* xb = x + (size_t)b * Tdim * Ddim;
    const float* const clampMax = x + (size_t)Bdim * Tdim * Ddim - 4;

    // async global->LDS staging (vmcnt only; lgkm untouched)
#define STAGE_TILE(TIDX, BUF) do {                                                     \
        const float* s0_ = xb + (size_t)(TIDX) * TB * Ddim + lane * 4;                 \
        _Pragma("unroll")                                                              \
        for (int k = 0; k < 10; ++k) {                                                 \
            const float* gp_ = s0_ + k * 256;                                          \
            if (gp_ > clampMax) gp_ = clampMax;                                        \
            __builtin_amdgcn_global_load_lds(                                          \
                (const __attribute__((address_space(1))) unsigned int*)gp_,            \
                (__attribute__((address_space(3))) unsigned int*)&xs[BUF][k * 256],    \
                16, 0, 0);                                                             \
        }                                                                              \
    } while (0)

    STAGE_TILE(0, 0);
    asm volatile("s_waitcnt vmcnt(0)" ::: "memory");

    // probe v_permlane32_swap_b32 direction (wave-uniform; works under either
    // half-swap semantic because per-half values are uniform)
    int pv = (lane < 32) ? 111 : 222;
    int pc = pv;
    asm volatile("v_permlane32_swap_b32 %0, %1" : "+v"(pv), "+v"(pc));
    const bool dir0 = (__builtin_amdgcn_readfirstlane(pv) == 222);
    // dir0: first operand ends holding the HIGH half's (odd-quad) data

    float    mem0 = 0.f, mem1 = 0.f;
    unsigned cnt0 = 0u,  cnt1 = 0u;
    float    addB0 = biasA, addB1 = biasB;
    const uint32_t hoff = (uint32_t)((lane >> 5) << 4);   // +16B for high half-wave

    auto mainbody = [&](auto dtag) {
        constexpr int DIR = decltype(dtag)::v;
        f32x4 ring[2][5];
        int buf = 0;

#define ISSUEG(S, GA)                                                                    \
        asm volatile("ds_read_b128 %0, %1 offset:0"   : "=v"(ring[S][0]) : "v"(GA));     \
        asm volatile("ds_read_b128 %0, %1 offset:32"  : "=v"(ring[S][1]) : "v"(GA));     \
        asm volatile("ds_read_b128 %0, %1 offset:64"  : "=v"(ring[S][2]) : "v"(GA));     \
        asm volatile("ds_read_b128 %0, %1 offset:96"  : "=v"(ring[S][3]) : "v"(GA));     \
        asm volatile("ds_read_b128 %0, %1 offset:128" : "=v"(ring[S][4]) : "v"(GA));

        // split quad-pair -> both quads wave-uniform via permlane32_swap
#define DOPAIR(RQ, WE0, WE1, AE0, AE1, BE0, BE1, FE,  WO0, WO1, AO0, AO1, BO0, BO1, FO)  \
        { float r0_=(RQ)[0], r1_=(RQ)[1], r2_=(RQ)[2], r3_=(RQ)[3];                      \
          float c0_=r0_, c1_=r1_, c2_=r2_, c3_=r3_;                                      \
          asm volatile("v_permlane32_swap_b32 %0, %1" : "+v"(r0_), "+v"(c0_));           \
          asm volatile("v_permlane32_swap_b32 %0, %1" : "+v"(r1_), "+v"(c1_));           \
          asm volatile("v_permlane32_swap_b32 %0, %1" : "+v"(r2_), "+v"(c2_));           \
          asm volatile("v_permlane32_swap_b32 %0, %1" : "+v"(r3_), "+v"(c3_));           \
          const float e0_ = (DIR==0)?c0_:r0_, e1_ = (DIR==0)?c1_:r1_,                    \
                      e2_ = (DIR==0)?c2_:r2_, e3_ = (DIR==0)?c3_:r3_;                    \
          const float o0_ = (DIR==0)?r0_:c0_, o1_ = (DIR==0)?r1_:c1_,                    \
                      o2_ = (DIR==0)?r2_:c2_, o3_ = (DIR==0)?r3_:c3_;                    \
          { f32x2 plo = {e0_, e1_}, phi = {e2_, e3_};                                    \
            FE(AE0, plo, wA[WE0]); FE(BE0, plo, wB[WE0]);                                \
            FE(AE1, phi, wA[WE1]); FE(BE1, phi, wB[WE1]); }                              \
          { f32x2 plo = {o0_, o1_}, phi = {o2_, o3_};                                    \
            FO(AO0, plo, wA[WO0]); FO(BO0, plo, wB[WO0]);                                \
            FO(AO1, phi, wA[WO1]); FO(BO1, phi, wB[WO1]); } }

        // one 2-step group from ring slot S (40 floats = 2 rows of 20)
#define COMPUTE(S)                                                                        \
        { f32x2 aA0,aA1,aB0,aB1,bA0,bA1,bB0,bB1;                                          \
          DOPAIR(ring[S][0], 0,1, aA0,aA1,aB0,aB1, PKMUL,  2,3, aA0,aA1,aB0,aB1, PKFMA)   \
          DOPAIR(ring[S][1], 4,5, aA0,aA1,aB0,aB1, PKFMA,  6,7, aA0,aA1,aB0,aB1, PKFMA)   \
          DOPAIR(ring[S][2], 8,9, aA0,aA1,aB0,aB1, PKFMA,  0,1, bA0,bA1,bB0,bB1, PKMUL)   \
          DOPAIR(ring[S][3], 2,3, bA0,bA1,bB0,bB1, PKFMA,  4,5, bA0,bA1,bB0,bB1, PKFMA)   \
          DOPAIR(ring[S][4], 6,7, bA0,bA1,bB0,bB1, PKFMA,  8,9, bA0,bA1,bB0,bB1, PKFMA)   \
          f32x2 sA, sB;                                                                   \
          PKADD(sA, aA0, aA1); PKADD(sB, aB0, aB1);                                       \
          float dA = sA[0] + sA[1], dB = sB[0] + sB[1];                                   \
          mem0 = fmaf(BETA, mem0, dA) + addB0;                                            \
          { const bool sp = mem0 > THR; cnt0 += sp ? 1u : 0u; addB0 = sp ? biasAm : biasA; } \
          mem1 = fmaf(BETA, mem1, dB) + addB1;                                            \
          { const bool sp = mem1 > THR; cnt1 += sp ? 1u : 0u; addB1 = sp ? biasBm : biasB; } \
          PKADD(sA, bA0, bA1); PKADD(sB, bB0, bB1);                                       \
          dA = sA[0] + sA[1]; dB = sB[0] + sB[1];                                         \
          mem0 = fmaf(BETA, mem0, dA) + addB0;                                            \
          { const bool sp = mem0 > THR; cnt0 += sp ? 1u : 0u; addB0 = sp ? biasAm : biasA; } \
          mem1 = fmaf(BETA, mem1, dB) + addB1;                                            \
          { const bool sp = mem1 > THR; cnt1 += sp ? 1u : 0u; addB1 = sp ? biasBm : biasB; } }

        for (int tile = 0; tile < NTILES; ++tile) {
            const int nt = (tile == NTILES - 1) ? (Tdim - TB * (NTILES - 1)) : TB;  // 80 or 128
            const int NG = nt >> 1;   // 2-step groups (40 or 64, both even)

            if (tile + 1 < NTILES) STAGE_TILE(tile + 1, buf ^ 1);

            uint32_t ab = (uint32_t)(uintptr_t)&xs[buf][0] + hoff;
            ISSUEG(0, ab)

            for (int gp = 0; gp < NG; gp += 2) {
                const uint32_t n1 = ab + 160u;
                ISSUEG(1, n1)
                asm volatile("s_waitcnt lgkmcnt(5)" ::: "memory");
                __builtin_amdgcn_sched_barrier(0);
                COMPUTE(0)
                const uint32_t n2 = n1 + 160u;
                ISSUEG(0, n2)                    // last iter: phantom group in pad
                asm volatile("s_waitcnt lgkmcnt(5)" ::: "memory");
                __builtin_amdgcn_sched_barrier(0);
                COMPUTE(1)
                ab = n2;
            }

            asm volatile("s_waitcnt lgkmcnt(0)" ::: "memory");  // drain phantoms
            asm volatile("s_waitcnt vmcnt(0)"  ::: "memory");   // next tile staged
            buf ^= 1;
        }
    };

    if (dir0) mainbody(ICst<0>{});
    else      mainbody(ICst<1>{});

    // fused epilogue — single wave, lgkm drained above
    cnt_s[lane]      = (float)cnt0;
    cnt_s[lane + 64] = (float)cnt1;
    __builtin_amdgcn_sched_barrier(0);
    if (lane < Cdim) {
        float dot = 0.0f;
#pragma unroll
        for (int k = 0; k < Hdim; ++k)
            dot = fmaf(cnt_s[k], W2[lane * Hdim + k], dot);
        const float Tf = (float)Tdim;
        const float scale = 1.0f / Tf + 0.1f / (Tf + 1e-6f);
        out[b * Cdim + lane] = fmaf(dot, scale, 1.1f * b2[lane]);
    }
}

extern "C" void kernel_launch(void* const* d_in, const int* in_sizes, int n_in,
                              void* d_out, int out_size, void* d_ws, size_t ws_size,
                              hipStream_t stream) {
    const float* x  = (const float*)d_in[0];
    const float* W1 = (const float*)d_in[1];
    const float* b1 = (const float*)d_in[2];
    const float* W2 = (const float*)d_in[3];
    const float* b2 = (const float*)d_in[4];
    float* out = (float*)d_out;

    snn_fused_kernel<<<dim3(Bdim), dim3(64), 0, stream>>>(x, W1, b1, W2, b2, out);
}

// Round 8
// 100.053 us; speedup vs baseline: 2.8508x; 2.7163x over previous
//
#include <hip/hip_runtime.h>
#include <stdint.h>

#define Bdim 512
#define Tdim 2000
#define Ddim 20
#define Hdim 128
#define Cdim 10
#define TT   64              // timesteps per chunk
#define NCH  32              // 31 full + 16-step tail
#define BETA 0.95f
#define THR  0.8f

typedef float f32x2 __attribute__((ext_vector_type(2)));
typedef float f32x4 __attribute__((ext_vector_type(4)));
typedef int   i32x4 __attribute__((ext_vector_type(4)));

#define MFMA_B16(ACC, A8, B8) \
  asm volatile("v_mfma_f32_16x16x32_bf16 %0, %1, %2, %0" : "+v"(ACC) : "v"(A8), "v"(B8));

__global__ __launch_bounds__(128, 1) void snn_mfma_kernel(
    const float* __restrict__ x,   // [B,T,D]
    const float* __restrict__ W1,  // [H,D]
    const float* __restrict__ b1,  // [H]
    const float* __restrict__ W2,  // [C,H]
    const float* __restrict__ b2,  // [C]
    float* __restrict__ out)       // [B,C]
{
  const int b   = blockIdx.x;
  const int tid = threadIdx.x;   // 0..127
  const int wid = tid >> 6;      // wave id: h-half
  const int l   = tid & 63;

  // LDS: x staging (dbuf) | A operand bf16 hi/lo (144 B/row padded) | cur [h][t]
  __shared__ __align__(16) float    xraw[2][TT * Ddim];   // 2 x 5120 B
  __shared__ __align__(16) uint32_t Alds[TT * 36];        // 9216 B (row: 16 hi dw | 16 lo dw | 4 pad)
  __shared__ __align__(16) float    curls[8728];          // 128 rows x 272 B + phantom pad
  __shared__ float cnt_s[Hdim];

  // one-time zero (K-pad region of Alds must stay 0 forever; cvt never writes it)
  for (int i = tid; i < TT * 36; i += 128) Alds[i] = 0u;

  // ---- B fragments: W1 rows -> bf16 hi/lo, frag layout (col=l&15, k=8*(l>>4)+j) ----
  i32x4 bhi[4], blo[4];
  {
    const int g  = l >> 4;
    const int hr = l & 15;
#pragma unroll
    for (int ni = 0; ni < 4; ++ni) {
      const int hh = wid * 64 + ni * 16 + hr;
      float wv[8];
#pragma unroll
      for (int j = 0; j < 8; ++j) {
        const int k = 8 * g + j;
        wv[j] = (k < Ddim) ? W1[hh * Ddim + k] : 0.0f;
      }
#pragma unroll
      for (int d = 0; d < 4; ++d) {
        const uint32_t u0 = __float_as_uint(wv[2*d]), u1 = __float_as_uint(wv[2*d+1]);
        const uint32_t h0 = (u0 + 0x8000u) & 0xFFFF0000u;
        const uint32_t h1 = (u1 + 0x8000u) & 0xFFFF0000u;
        bhi[ni][d] = (int)(h1 | (h0 >> 16));
        const float l0 = wv[2*d]   - __uint_as_float(h0);
        const float l1 = wv[2*d+1] - __uint_as_float(h1);
        const uint32_t e0 = (__float_as_uint(l0) + 0x8000u) & 0xFFFF0000u;
        const uint32_t e1 = (__float_as_uint(l1) + 0x8000u) & 0xFFFF0000u;
        blo[ni][d] = (int)(e1 | (e0 >> 16));
      }
    }
  }

  const float bias  = b1[tid];
  const float biasm = bias - THR;

  const float* xb = x + (size_t)b * (Tdim * Ddim);
  const float* const clampMax = x + (size_t)Bdim * Tdim * Ddim - 4;

  const uint32_t AbaseB = (uint32_t)(uintptr_t)&Alds[0];
  const uint32_t curB   = (uint32_t)(uintptr_t)&curls[0];
  const uint32_t afbase = AbaseB + 144u * (uint32_t)(l & 15) + 16u * (uint32_t)(l >> 4);
  const uint32_t cwbase = curB + 272u * (uint32_t)(wid * 64 + (l & 15)) + 16u * (uint32_t)(l >> 4);
  const uint32_t sbase  = curB + 272u * (uint32_t)tid;

  // 5120 B chunk: 2 full-block DMA ops + 1 wave0-only (vmcnt: wave0=3, wave1=2)
#define STAGE(CH, BUF) do {                                                            \
    _Pragma("unroll")                                                                  \
    for (int k_ = 0; k_ < 2; ++k_) {                                                   \
      const float* gp_ = xb + (CH) * 1280 + k_ * 512 + tid * 4;                        \
      if (gp_ > clampMax) gp_ = clampMax;                                              \
      __builtin_amdgcn_global_load_lds(                                                \
        (const __attribute__((address_space(1))) unsigned int*)gp_,                    \
        (__attribute__((address_space(3))) unsigned int*)&xraw[BUF][k_ * 512 + tid * 4], \
        16, 0, 0);                                                                     \
    }                                                                                  \
    if (tid < 64) {                                                                    \
      const float* gp_ = xb + (CH) * 1280 + 1024 + tid * 4;                            \
      if (gp_ > clampMax) gp_ = clampMax;                                              \
      __builtin_amdgcn_global_load_lds(                                                \
        (const __attribute__((address_space(1))) unsigned int*)gp_,                    \
        (__attribute__((address_space(3))) unsigned int*)&xraw[BUF][1024 + tid * 4],   \
        16, 0, 0);                                                                     \
    }                                                                                  \
  } while (0)

  float mem = 0.0f, cnt = 0.0f, addB = bias;

  STAGE(0, 0);

#pragma unroll 1
  for (int ch = 0; ch < NCH; ++ch) {
    const int buf = ch & 1;
    if (ch + 1 < NCH) {
      if (buf) STAGE(ch + 1, 0); else STAGE(ch + 1, 1);
      if (tid < 64) asm volatile("s_waitcnt vmcnt(3)" ::: "memory");
      else          asm volatile("s_waitcnt vmcnt(2)" ::: "memory");
    } else {
      asm volatile("s_waitcnt vmcnt(0)" ::: "memory");
    }
    __syncthreads();   // BARRIER A: x chunk landed (each wave waited its own vmcnt)

    // ---- convert: xraw[buf] -> Alds (bf16 round-split hi/lo, frag-ready) ----
    {
      const int row = tid >> 1, half = tid & 1;
      const float* xr = &xraw[buf][0] + 20 * row + 10 * half;
      float v[10];
#pragma unroll
      for (int j = 0; j < 10; ++j) v[j] = xr[j];
      uint32_t* Arow = &Alds[36 * row + 5 * half];
#pragma unroll
      for (int d = 0; d < 5; ++d) {
        const uint32_t u0 = __float_as_uint(v[2*d]), u1 = __float_as_uint(v[2*d+1]);
        const uint32_t h0 = (u0 + 0x8000u) & 0xFFFF0000u;
        const uint32_t h1 = (u1 + 0x8000u) & 0xFFFF0000u;
        Arow[d] = h1 | (h0 >> 16);
        const float l0 = v[2*d]   - __uint_as_float(h0);
        const float l1 = v[2*d+1] - __uint_as_float(h1);
        const uint32_t e0 = (__float_as_uint(l0) + 0x8000u) & 0xFFFF0000u;
        const uint32_t e1 = (__float_as_uint(l1) + 0x8000u) & 0xFFFF0000u;
        Arow[16 + d] = e1 | (e0 >> 16);
      }
    }
    __syncthreads();   // BARRIER B: Alds complete (GEMM reads all rows)

    // ---- GEMM: cur[h][t] = x . W1^T via bf16x3 MFMA ----
#define GEMM_MT(MT, AC)                                                                        \
    {                                                                                          \
      i32x4 ah_, al_;                                                                          \
      asm volatile("ds_read_b128 %0, %1 offset:%c2" : "=v"(ah_) : "v"(afbase), "n"(2304*MT));  \
      asm volatile("ds_read_b128 %0, %1 offset:%c2" : "=v"(al_) : "v"(afbase), "n"(2304*MT+64)); \
      AC[0] = z4; AC[1] = z4; AC[2] = z4; AC[3] = z4;                                          \
      asm volatile("s_waitcnt lgkmcnt(0)" ::: "memory");                                       \
      __builtin_amdgcn_sched_barrier(0);                                                       \
      asm volatile("s_nop 2");                                                                 \
      MFMA_B16(AC[0], al_, bhi[0]) MFMA_B16(AC[1], al_, bhi[1])                                \
      MFMA_B16(AC[2], al_, bhi[2]) MFMA_B16(AC[3], al_, bhi[3])                                \
      MFMA_B16(AC[0], ah_, blo[0]) MFMA_B16(AC[1], ah_, blo[1])                                \
      MFMA_B16(AC[2], ah_, blo[2]) MFMA_B16(AC[3], ah_, blo[3])                                \
      MFMA_B16(AC[0], ah_, bhi[0]) MFMA_B16(AC[1], ah_, bhi[1])                                \
      MFMA_B16(AC[2], ah_, bhi[2]) MFMA_B16(AC[3], ah_, bhi[3])                                \
      asm volatile("s_nop 7"); asm volatile("s_nop 4");                                        \
      asm volatile("ds_write_b128 %0, %1 offset:%c2" :: "v"(cwbase), "v"(AC[0]), "n"(64*MT));      \
      asm volatile("ds_write_b128 %0, %1 offset:%c2" :: "v"(cwbase), "v"(AC[1]), "n"(4352+64*MT)); \
      asm volatile("ds_write_b128 %0, %1 offset:%c2" :: "v"(cwbase), "v"(AC[2]), "n"(8704+64*MT)); \
      asm volatile("ds_write_b128 %0, %1 offset:%c2" :: "v"(cwbase), "v"(AC[3]), "n"(13056+64*MT)); \
    }
    {
      const f32x4 z4 = {0.f, 0.f, 0.f, 0.f};
      f32x4 accA[4], accB[4];
      GEMM_MT(0, accA)
      GEMM_MT(1, accB)
      GEMM_MT(2, accA)
      GEMM_MT(3, accB)
    }
    asm volatile("s_waitcnt lgkmcnt(0)" ::: "memory");   // drain C-writes (clean lgkm for ring)
    __builtin_amdgcn_sched_barrier(0);

    // ---- scan: own-wave-written rows, depth-8 b64 ring, no barrier ----
    {
      uint32_t sa = sbase;
      f32x2 r0, r1, r2, r3, r4, r5, r6, r7;
#define RDB64(R, OFF) asm volatile("ds_read_b64 %0, %1 offset:%c2" : "=v"(R) : "v"(sa), "n"(OFF));
#define SSTEP(CV) {                                          \
        mem = fmaf(BETA, mem, (CV)) + addB;                  \
        const bool sp_ = mem > THR;                          \
        cnt += sp_ ? 1.0f : 0.0f;                            \
        addB = sp_ ? biasm : bias; }
#define SPAIR(R) { const float c0_ = (R)[0], c1_ = (R)[1]; SSTEP(c0_) SSTEP(c1_) }
      RDB64(r0, 0)  RDB64(r1, 8)  RDB64(r2, 16) RDB64(r3, 24)
      RDB64(r4, 32) RDB64(r5, 40) RDB64(r6, 48) RDB64(r7, 56)
      const int G2 = (ch == NCH - 1) ? 1 : 4;
#pragma unroll 1
      for (int g2 = 0; g2 < G2; ++g2) {
        asm volatile("s_waitcnt lgkmcnt(4)" ::: "memory");
        __builtin_amdgcn_sched_barrier(0);
        SPAIR(r0) SPAIR(r1) SPAIR(r2) SPAIR(r3)
        RDB64(r0, 64) RDB64(r1, 72) RDB64(r2, 80) RDB64(r3, 88)
        asm volatile("s_waitcnt lgkmcnt(4)" ::: "memory");
        __builtin_amdgcn_sched_barrier(0);
        SPAIR(r4) SPAIR(r5) SPAIR(r6) SPAIR(r7)
        RDB64(r4, 96) RDB64(r5, 104) RDB64(r6, 112) RDB64(r7, 120)
        asm volatile("v_add_u32 %0, 64, %0" : "+v"(sa));
      }
      asm volatile("s_waitcnt lgkmcnt(0)" ::: "memory");   // drain phantoms
#undef RDB64
#undef SSTEP
#undef SPAIR
    }
  }

  // ---- fused epilogue: logits from spike counts ----
  cnt_s[tid] = cnt;
  __syncthreads();
  if (tid < Cdim) {
    float dot = 0.0f;
#pragma unroll
    for (int k = 0; k < Hdim; ++k)
      dot = fmaf(cnt_s[k], W2[tid * Hdim + k], dot);
    const float Tf = (float)Tdim;
    const float scale = 1.0f / Tf + 0.1f / (Tf + 1e-6f);
    out[b * Cdim + tid] = fmaf(dot, scale, 1.1f * b2[tid]);
  }
}

extern "C" void kernel_launch(void* const* d_in, const int* in_sizes, int n_in,
                              void* d_out, int out_size, void* d_ws, size_t ws_size,
                              hipStream_t stream) {
  const float* x  = (const float*)d_in[0];
  const float* W1 = (const float*)d_in[1];
  const float* b1 = (const float*)d_in[2];
  const float* W2 = (const float*)d_in[3];
  const float* b2 = (const float*)d_in[4];
  float* out = (float*)d_out;

  snn_mfma_kernel<<<dim3(Bdim), dim3(128), 0, stream>>>(x, W1, b1, W2, b2, out);
}

// Round 9
// 87.430 us; speedup vs baseline: 3.2624x; 1.1444x over previous
//
#include <hip/hip_runtime.h>
#include <stdint.h>

#define Bdim 512
#define Tdim 2000
#define Ddim 20
#define Hdim 128
#define Cdim 10
#define TT   64              // timesteps per chunk
#define NCH  32              // 31 full + 16-step tail
#define BETA 0.95f
#define THR  0.8f

typedef float f32x2 __attribute__((ext_vector_type(2)));
typedef float f32x4 __attribute__((ext_vector_type(4)));
typedef int   i32x4 __attribute__((ext_vector_type(4)));

__global__ __launch_bounds__(128, 1) void snn_mfma2_kernel(
    const float* __restrict__ x,   // [B,T,D]
    const float* __restrict__ W1,  // [H,D]
    const float* __restrict__ b1,  // [H]
    const float* __restrict__ W2,  // [C,H]
    const float* __restrict__ b2,  // [C]
    float* __restrict__ out)       // [B,C]
{
  const int b   = blockIdx.x;
  const int tid = threadIdx.x;   // 0..127
  const int wid = tid >> 6;      // wave: h-half
  const int l   = tid & 63;
  const int r   = l & 15;        // A/C fragment row-col index
  const int g   = l >> 4;        // k-group / t-subrow index

  __shared__ __align__(16) float xraw[2][TT * Ddim];        // 10240 B, f32 staging
  __shared__ __align__(16) float cur[(TT + 8) * 132];       // t-major, 132 dw stride, +8 rows phantom pad
  __shared__ float cnt_s[Hdim];

  // zero the chunk-0 uninit-LDS hazard region (A-frag g>=2 phantom reads can
  // overflow into xraw[1] head before its first DMA). Both waves write same zeros.
  if (l < 16) xraw[1][l] = 0.0f;

  // ---- B fragments: W1 rows -> bf16 hi/lo (layout verified in r8) ----
  i32x4 bhi[4], blo[4];
  {
#pragma unroll
    for (int ni = 0; ni < 4; ++ni) {
      const int hh = wid * 64 + ni * 16 + r;
      float wv[8];
#pragma unroll
      for (int j = 0; j < 8; ++j) {
        const int k = 8 * g + j;
        wv[j] = (k < Ddim) ? W1[hh * Ddim + k] : 0.0f;
      }
#pragma unroll
      for (int d = 0; d < 4; ++d) {
        const uint32_t u0 = __float_as_uint(wv[2*d]), u1 = __float_as_uint(wv[2*d+1]);
        const uint32_t h0 = (u0 + 0x8000u) & 0xFFFF0000u;
        const uint32_t h1 = (u1 + 0x8000u) & 0xFFFF0000u;
        bhi[ni][d] = (int)(h1 | (h0 >> 16));
        const float l0 = wv[2*d]   - __uint_as_float(h0);
        const float l1 = wv[2*d+1] - __uint_as_float(h1);
        const uint32_t e0 = (__float_as_uint(l0) + 0x8000u) & 0xFFFF0000u;
        const uint32_t e1 = (__float_as_uint(l1) + 0x8000u) & 0xFFFF0000u;
        blo[ni][d] = (int)(e1 | (e0 >> 16));
      }
    }
  }

  const float bias  = b1[tid];
  const float biasm = bias - THR;

  const float* xb = x + (size_t)b * (Tdim * Ddim);
  const float* const clampMax = x + (size_t)Bdim * Tdim * Ddim - 4;

  const uint32_t xrawB = (uint32_t)(uintptr_t)&xraw[0][0];
  const uint32_t curB  = (uint32_t)(uintptr_t)&cur[0];

  // staging: 5120 B/chunk as 5 x 1024B DMA; wave0 takes 3, wave1 takes 2
#define STAGE_ONE(CH, BUF, I) {                                                        \
    const float* gp_ = xb + (CH) * 1280 + (I) * 256 + l * 4;                           \
    if (gp_ > clampMax) gp_ = clampMax;                                                \
    __builtin_amdgcn_global_load_lds(                                                  \
      (const __attribute__((address_space(1))) unsigned int*)gp_,                      \
      (__attribute__((address_space(3))) unsigned int*)&xraw[BUF][(I) * 256 + l * 4],  \
      16, 0, 0); }
#define STAGE(CH, BUF) do {                                                            \
    if (wid == 0) { STAGE_ONE(CH, BUF, 0) STAGE_ONE(CH, BUF, 1) STAGE_ONE(CH, BUF, 2) } \
    else          { STAGE_ONE(CH, BUF, 3) STAGE_ONE(CH, BUF, 4) } } while (0)

  // f32 pair -> packed bf16 hi + packed bf16 lo (RNE via v_cvt_pk_bf16_f32)
#define CVT_HILO(HI, LO, F0, F1) {                                                     \
    asm volatile("v_cvt_pk_bf16_f32 %0, %1, %2" : "=v"(HI) : "v"(F0), "v"(F1));        \
    const float h0f_ = __uint_as_float((HI) << 16);                                    \
    const float h1f_ = __uint_as_float((HI) & 0xFFFF0000u);                            \
    const float l0_ = (F0) - h0f_;  const float l1_ = (F1) - h1f_;                     \
    asm volatile("v_cvt_pk_bf16_f32 %0, %1, %2" : "=v"(LO) : "v"(l0_), "v"(l1_)); }

#define MFMA0(ACC, A8, B8) \
  asm volatile("v_mfma_f32_16x16x32_bf16 %0, %1, %2, 0"  : "=v"(ACC) : "v"(A8), "v"(B8));
#define MFMA(ACC, A8, B8)  \
  asm volatile("v_mfma_f32_16x16x32_bf16 %0, %1, %2, %0" : "+v"(ACC) : "v"(A8), "v"(B8));

#define ARD(MT)                                                                        \
  asm volatile("ds_read_b128 %0, %1 offset:%c2" : "=v"(araw[MT][0]) : "v"(ab), "n"((MT)*1280));    \
  asm volatile("ds_read_b128 %0, %1 offset:%c2" : "=v"(araw[MT][1]) : "v"(ab), "n"((MT)*1280+16));

#define ACVT(MT)                                                                       \
  i32x4 ahi##MT, alo##MT;                                                              \
  { uint32_t h_, lo_;                                                                  \
    CVT_HILO(h_, lo_, araw[MT][0][0], araw[MT][0][1]) ahi##MT[0] = (int)h_; alo##MT[0] = (int)lo_; \
    CVT_HILO(h_, lo_, araw[MT][0][2], araw[MT][0][3]) ahi##MT[1] = (int)h_; alo##MT[1] = (int)lo_; \
    CVT_HILO(h_, lo_, araw[MT][1][0], araw[MT][1][1]) ahi##MT[2] = (int)h_; alo##MT[2] = (int)lo_; \
    CVT_HILO(h_, lo_, araw[MT][1][2], araw[MT][1][3]) ahi##MT[3] = (int)h_; alo##MT[3] = (int)lo_; }

#define AMM(MT)                                                                        \
  asm volatile("s_nop 2");                                                             \
  MFMA0(acc[MT][0], alo##MT, bhi[0]) MFMA0(acc[MT][1], alo##MT, bhi[1])                \
  MFMA0(acc[MT][2], alo##MT, bhi[2]) MFMA0(acc[MT][3], alo##MT, bhi[3])                \
  MFMA (acc[MT][0], ahi##MT, blo[0]) MFMA (acc[MT][1], ahi##MT, blo[1])                \
  MFMA (acc[MT][2], ahi##MT, blo[2]) MFMA (acc[MT][3], ahi##MT, blo[3])                \
  MFMA (acc[MT][0], ahi##MT, bhi[0]) MFMA (acc[MT][1], ahi##MT, bhi[1])                \
  MFMA (acc[MT][2], ahi##MT, bhi[2]) MFMA (acc[MT][3], ahi##MT, bhi[3])

  // t-major C-writes: rows t = MT*16 + 4g + reg, col = 64*wid + 16n + r (conflict-free)
#define CWR(MT) {                                                                      \
    const uint32_t w0_ = cw0 + (MT) * 8448u;  const uint32_t w1_ = w0_ + 1056u;        \
    asm volatile("ds_write2_b32 %0, %1, %2 offset0:0 offset1:132"  :: "v"(w0_), "v"(acc[MT][0][0]), "v"(acc[MT][0][1])); \
    asm volatile("ds_write2_b32 %0, %1, %2 offset0:0 offset1:132"  :: "v"(w1_), "v"(acc[MT][0][2]), "v"(acc[MT][0][3])); \
    asm volatile("ds_write2_b32 %0, %1, %2 offset0:16 offset1:148" :: "v"(w0_), "v"(acc[MT][1][0]), "v"(acc[MT][1][1])); \
    asm volatile("ds_write2_b32 %0, %1, %2 offset0:16 offset1:148" :: "v"(w1_), "v"(acc[MT][1][2]), "v"(acc[MT][1][3])); \
    asm volatile("ds_write2_b32 %0, %1, %2 offset0:32 offset1:164" :: "v"(w0_), "v"(acc[MT][2][0]), "v"(acc[MT][2][1])); \
    asm volatile("ds_write2_b32 %0, %1, %2 offset0:32 offset1:164" :: "v"(w1_), "v"(acc[MT][2][2]), "v"(acc[MT][2][3])); \
    asm volatile("ds_write2_b32 %0, %1, %2 offset0:48 offset1:180" :: "v"(w0_), "v"(acc[MT][3][0]), "v"(acc[MT][3][1])); \
    asm volatile("ds_write2_b32 %0, %1, %2 offset0:48 offset1:180" :: "v"(w1_), "v"(acc[MT][3][2]), "v"(acc[MT][3][3])); }

#define LG0() asm volatile("s_waitcnt lgkmcnt(0)" ::: "memory"); __builtin_amdgcn_sched_barrier(0);
#define LG3() asm volatile("s_waitcnt lgkmcnt(3)" ::: "memory"); __builtin_amdgcn_sched_barrier(0);

#define SSTEP(CV) {                                                                    \
    mem = fmaf(BETA, mem, (CV)) + addB;                                                \
    const bool sp_ = mem > THR;                                                        \
    cnt += sp_ ? 1u : 0u;                                                              \
    addB = sp_ ? biasm : bias; }
#define SISS(PR, SPA) asm volatile("ds_read2_b32 %0, %1 offset0:0 offset1:132" : "=v"(PR) : "v"(SPA));
#define SCONS(PR) { SSTEP(PR[0]) SSTEP(PR[1]) }

  // scan NPAIRS pairs of steps; depth-4 read2 ring; phantom issues land in cur's pad rows
#define SCAN(NPAIRS) {                                                                 \
    uint32_t sp = curB + 256u * (uint32_t)wid + 4u * (uint32_t)l;                      \
    f32x2 pr0, pr1, pr2, pr3;                                                          \
    SISS(pr0, sp) SISS(pr1, sp + 1056u) SISS(pr2, sp + 2112u) SISS(pr3, sp + 3168u)    \
    sp += 4224u;                                                                       \
    _Pragma("unroll 1")                                                                \
    for (int p = 0; p < (NPAIRS); p += 4) {                                            \
      LG3() SCONS(pr0) SISS(pr0, sp)                                                   \
      LG3() SCONS(pr1) SISS(pr1, sp + 1056u)                                           \
      LG3() SCONS(pr2) SISS(pr2, sp + 2112u)                                           \
      LG3() SCONS(pr3) SISS(pr3, sp + 3168u)                                           \
      sp += 4224u; }                                                                   \
    asm volatile("s_waitcnt lgkmcnt(0)" ::: "memory"); }

  float mem = 0.0f, addB = bias;
  uint32_t cnt = 0u;

  STAGE(0, 0);

#pragma unroll 1
  for (int ch = 0; ch < NCH; ++ch) {
    const int buf = ch & 1;
    asm volatile("s_waitcnt vmcnt(0)" ::: "memory");   // own stage done
    __syncthreads();                                   // both waves' stages done
    if (ch + 1 < NCH) { if (buf == 0) STAGE(ch + 1, 1); else STAGE(ch + 1, 0); }

    const uint32_t ab  = xrawB + (uint32_t)buf * 5120u + 4u * (20u * (uint32_t)r + 8u * (uint32_t)g);
    const uint32_t cw0 = curB + 4u * (132u * 4u * (uint32_t)g + 64u * (uint32_t)wid + (uint32_t)r);

    if (ch != NCH - 1) {
      f32x4 araw[4][2];
      f32x4 acc[4][4];
      ARD(0) ARD(1) ARD(2) ARD(3)
      LG0()
      ACVT(0) AMM(0)
      ACVT(1) AMM(1)
      ACVT(2) AMM(2)
      ACVT(3) AMM(3)
      asm volatile("s_nop 7"); asm volatile("s_nop 4");
      CWR(0) CWR(1) CWR(2) CWR(3)
      LG0()
      SCAN(32)
    } else {
      f32x4 araw[1][2];
      f32x4 acc[1][4];
      ARD(0)
      LG0()
      ACVT(0) AMM(0)
      asm volatile("s_nop 7"); asm volatile("s_nop 4");
      CWR(0)
      LG0()
      SCAN(8)
    }
  }

  // ---- fused epilogue: logits from spike counts ----
  cnt_s[tid] = (float)cnt;
  __syncthreads();
  if (tid < Cdim) {
    float dot = 0.0f;
#pragma unroll
    for (int k = 0; k < Hdim; ++k)
      dot = fmaf(cnt_s[k], W2[tid * Hdim + k], dot);
    const float Tf = (float)Tdim;
    const float scale = 1.0f / Tf + 0.1f / (Tf + 1e-6f);
    out[b * Cdim + tid] = fmaf(dot, scale, 1.1f * b2[tid]);
  }
}

extern "C" void kernel_launch(void* const* d_in, const int* in_sizes, int n_in,
                              void* d_out, int out_size, void* d_ws, size_t ws_size,
                              hipStream_t stream) {
  const float* x  = (const float*)d_in[0];
  const float* W1 = (const float*)d_in[1];
  const float* b1 = (const float*)d_in[2];
  const float* W2 = (const float*)d_in[3];
  const float* b2 = (const float*)d_in[4];
  float* out = (float*)d_out;

  snn_mfma2_kernel<<<dim3(Bdim), dim3(128), 0, stream>>>(x, W1, b1, W2, b2, out);
}

// Round 10
// 62.200 us; speedup vs baseline: 4.5858x; 1.4056x over previous
//
#include <hip/hip_runtime.h>
#include <stdint.h>

#define Bdim 512
#define Tdim 2000
#define Ddim 20
#define Hdim 128
#define Cdim 10
#define TT   64
#define NCH  32              // 31 full chunks + 16-step tail
#define BETA 0.95f
#define THR  0.8f

typedef float f32x2 __attribute__((ext_vector_type(2)));
typedef float f32x4 __attribute__((ext_vector_type(4)));
typedef int   i32x4 __attribute__((ext_vector_type(4)));

// f32 pair -> packed bf16 hi + packed bf16 lo (RNE)
#define CVT_HILO(HI, LO, F0, F1) {                                                     \
    asm volatile("v_cvt_pk_bf16_f32 %0, %1, %2" : "=v"(HI) : "v"(F0), "v"(F1));        \
    const float h0f_ = __uint_as_float((HI) << 16);                                    \
    const float h1f_ = __uint_as_float((HI) & 0xFFFF0000u);                            \
    const float l0_ = (F0) - h0f_;  const float l1_ = (F1) - h1f_;                     \
    asm volatile("v_cvt_pk_bf16_f32 %0, %1, %2" : "=v"(LO) : "v"(l0_), "v"(l1_)); }

#define MFMA0(ACC, A8, B8) \
  asm volatile("v_mfma_f32_16x16x32_bf16 %0, %1, %2, 0"  : "=v"(ACC) : "v"(A8), "v"(B8));
#define MFMA(ACC, A8, B8)  \
  asm volatile("v_mfma_f32_16x16x32_bf16 %0, %1, %2, %0" : "+v"(ACC) : "v"(A8), "v"(B8));

__global__ __launch_bounds__(256, 1) void snn_spec_kernel(
    const float* __restrict__ x,   // [B,T,D]
    const float* __restrict__ W1,  // [H,D]
    const float* __restrict__ b1,  // [H]
    const float* __restrict__ W2,  // [C,H]
    const float* __restrict__ b2,  // [C]
    float* __restrict__ out)       // [B,C]
{
  const int b   = blockIdx.x;
  const int tid = threadIdx.x;    // 0..255
  const int wid = tid >> 6;       // 0,1: producers; 2,3: scanners
  const int l   = tid & 63;
  const int r   = l & 15;
  const int g   = l >> 4;

  __shared__ __align__(16) float xraw[2][TT * Ddim];    // 10240 B (rows of 20 f32)
  __shared__ __align__(16) float cur[2][TT * 132];      // 67584 B, t-major stride 132
  __shared__ float cnt_s[Hdim];

  const float* xb = x + (size_t)b * (Tdim * Ddim);
  const float* const clampMax = x + (size_t)Bdim * Tdim * Ddim - 4;

  const uint32_t xrawB = (uint32_t)(uintptr_t)&xraw[0][0];
  const uint32_t curB  = (uint32_t)(uintptr_t)&cur[0][0];

  // ---------------- producer-only setup ----------------
  i32x4 bhi[8], blo[8];
  f32x4 zero4, ovr;
  bool  sel23 = false, g3f = false;
  if (wid < 2) {
    const bool g2 = (g == 2);
    g3f   = (g == 3);
    sel23 = g2 | g3f;
    zero4[0]=0.f; zero4[1]=0.f; zero4[2]=0.f; zero4[3]=0.f;
    ovr = zero4; if (g2) ovr[0] = 1.0f;    // A column k=20 := 1.0 (bias rider)
#pragma unroll
    for (int ni = 0; ni < 8; ++ni) {
      const int hh = ni * 16 + r;
      float wv[8];
#pragma unroll
      for (int j = 0; j < 8; ++j) {
        const int k = 8 * g + j;
        wv[j] = (k < Ddim) ? W1[hh * Ddim + k] : ((k == Ddim) ? b1[hh] : 0.0f);
      }
#pragma unroll
      for (int d = 0; d < 4; ++d) {
        const uint32_t u0 = __float_as_uint(wv[2*d]), u1 = __float_as_uint(wv[2*d+1]);
        const uint32_t h0 = (u0 + 0x8000u) & 0xFFFF0000u;
        const uint32_t h1 = (u1 + 0x8000u) & 0xFFFF0000u;
        bhi[ni][d] = (int)(h1 | (h0 >> 16));
        const float l0 = wv[2*d]   - __uint_as_float(h0);
        const float l1 = wv[2*d+1] - __uint_as_float(h1);
        const uint32_t e0 = (__float_as_uint(l0) + 0x8000u) & 0xFFFF0000u;
        const uint32_t e1 = (__float_as_uint(l1) + 0x8000u) & 0xFFFF0000u;
        blo[ni][d] = (int)(e1 | (e0 >> 16));
      }
    }
  }

  // ---------------- scanner-only state ----------------
  float    mem = 0.0f;
  bool     sp  = false;
  uint32_t cnt = 0u;
  f32x2    negT2; negT2[0] = -THR; negT2[1] = -THR;
  const int sid = wid - 2;

  // Each producer wave stages ITS OWN 32 t-rows (2560 B) -> no cross-wave xraw dep.
#define STAGE(CH, BUF) do {                                                            \
    const float* g0_ = xb + (CH) * 1280 + wid * 640 + l * 4;                           \
    char* lb_ = (char*)&xraw[0][0] + (BUF) * 5120 + wid * 2560 + l * 16;               \
    const float* p0_ = g0_;        if (p0_ > clampMax) p0_ = clampMax;                 \
    const float* p1_ = g0_ + 256;  if (p1_ > clampMax) p1_ = clampMax;                 \
    __builtin_amdgcn_global_load_lds(                                                  \
      (const __attribute__((address_space(1))) unsigned int*)p0_,                      \
      (__attribute__((address_space(3))) unsigned int*)lb_, 16, 0, 0);                 \
    __builtin_amdgcn_global_load_lds(                                                  \
      (const __attribute__((address_space(1))) unsigned int*)p1_,                      \
      (__attribute__((address_space(3))) unsigned int*)(lb_ + 1024), 16, 0, 0);        \
    if (l < 32) {                                                                      \
      const float* p2_ = g0_ + 512;  if (p2_ > clampMax) p2_ = clampMax;               \
      __builtin_amdgcn_global_load_lds(                                                \
        (const __attribute__((address_space(1))) unsigned int*)p2_,                    \
        (__attribute__((address_space(3))) unsigned int*)(lb_ + 2048), 16, 0, 0);      \
    } } while (0)

  // one 16-t MFMA tile: xraw -> cvt(bf16 hi/lo) -> 24 MFMA (128 h) -> cur[pbuf]
#define GEMM_MT(MIDX) {                                                                \
    const int mt_ = 2 * wid + (MIDX);                                                  \
    const uint32_t afb_ = xrawB + (uint32_t)(pbuf * 5120 + mt_ * 1280 + 80 * r + 32 * g); \
    f32x4 a0_, a1_;                                                                    \
    asm volatile("ds_read_b128 %0, %1 offset:0"  : "=v"(a0_) : "v"(afb_));             \
    asm volatile("ds_read_b128 %0, %1 offset:16" : "=v"(a1_) : "v"(afb_));             \
    asm volatile("s_waitcnt lgkmcnt(0)" ::: "memory");                                 \
    __builtin_amdgcn_sched_barrier(0);                                                 \
    a0_ = g3f   ? zero4 : a0_;                                                         \
    a1_ = sel23 ? ovr   : a1_;                                                         \
    i32x4 ahi_, alo_;                                                                  \
    { uint32_t h_, lo_;                                                                \
      CVT_HILO(h_, lo_, a0_[0], a0_[1]) ahi_[0]=(int)h_; alo_[0]=(int)lo_;             \
      CVT_HILO(h_, lo_, a0_[2], a0_[3]) ahi_[1]=(int)h_; alo_[1]=(int)lo_;             \
      CVT_HILO(h_, lo_, a1_[0], a1_[1]) ahi_[2]=(int)h_; alo_[2]=(int)lo_;             \
      CVT_HILO(h_, lo_, a1_[2], a1_[3]) ahi_[3]=(int)h_; alo_[3]=(int)lo_; }           \
    asm volatile("s_nop 2");                                                           \
    f32x4 ac0,ac1,ac2,ac3,ac4,ac5,ac6,ac7;                                             \
    MFMA0(ac0, alo_, bhi[0]) MFMA0(ac1, alo_, bhi[1]) MFMA0(ac2, alo_, bhi[2])         \
    MFMA0(ac3, alo_, bhi[3]) MFMA0(ac4, alo_, bhi[4]) MFMA0(ac5, alo_, bhi[5])         \
    MFMA0(ac6, alo_, bhi[6]) MFMA0(ac7, alo_, bhi[7])                                  \
    MFMA (ac0, ahi_, blo[0]) MFMA (ac1, ahi_, blo[1]) MFMA (ac2, ahi_, blo[2])         \
    MFMA (ac3, ahi_, blo[3]) MFMA (ac4, ahi_, blo[4]) MFMA (ac5, ahi_, blo[5])         \
    MFMA (ac6, ahi_, blo[6]) MFMA (ac7, ahi_, blo[7])                                  \
    MFMA (ac0, ahi_, bhi[0]) MFMA (ac1, ahi_, bhi[1]) MFMA (ac2, ahi_, bhi[2])         \
    MFMA (ac3, ahi_, bhi[3]) MFMA (ac4, ahi_, bhi[4]) MFMA (ac5, ahi_, bhi[5])         \
    MFMA (ac6, ahi_, bhi[6]) MFMA (ac7, ahi_, bhi[7])                                  \
    asm volatile("s_nop 7"); asm volatile("s_nop 4");                                  \
    const uint32_t cwb_  = curB + (uint32_t)(pbuf * 33792 + 528 * (mt_ * 16 + 4 * g) + 4 * r); \
    const uint32_t cwb2_ = cwb_ + 1056u;                                               \
    CW2(0, ac0) CW2(1, ac1) CW2(2, ac2) CW2(3, ac3)                                    \
    CW2(4, ac4) CW2(5, ac5) CW2(6, ac6) CW2(7, ac7) }

#define CW2(NI, AC)                                                                    \
    asm volatile("ds_write2_b32 %0, %1, %2 offset0:%c3 offset1:%c4"                    \
                 :: "v"(cwb_),  "v"(AC[0]), "v"(AC[1]), "n"(16*(NI)), "n"(16*(NI)+132)); \
    asm volatile("ds_write2_b32 %0, %1, %2 offset0:%c3 offset1:%c4"                    \
                 :: "v"(cwb2_), "v"(AC[2]), "v"(AC[3]), "n"(16*(NI)), "n"(16*(NI)+132));

  // ---- scanner machinery: dual-fma 8-cyc chain, depth-8 read2 ring ----
#define RD2(PR, AD) asm volatile("ds_read2_b32 %0, %1 offset0:0 offset1:132" : "=v"(PR) : "v"(AD));
#define LGW(N) asm volatile("s_waitcnt lgkmcnt(" #N ")" ::: "memory"); __builtin_amdgcn_sched_barrier(0);
#define CONSUME(PR) {                                                                  \
    f32x2 cm_; asm("v_pk_add_f32 %0, %1, %2" : "=v"(cm_) : "v"(PR), "v"(negT2));       \
    float mP_ = fmaf(BETA, mem, PR[0]);                                                \
    float mM_ = fmaf(BETA, mem, cm_[0]);                                               \
    mem = sp ? mM_ : mP_;                                                              \
    sp  = mem > THR;                                                                   \
    cnt += sp ? 1u : 0u;                                                               \
    mP_ = fmaf(BETA, mem, PR[1]);                                                      \
    mM_ = fmaf(BETA, mem, cm_[1]);                                                     \
    mem = sp ? mM_ : mP_;                                                              \
    sp  = mem > THR;                                                                   \
    cnt += sp ? 1u : 0u; }
#define SSLOT(S) { LGW(7) CONSUME(pr##S) a##S += 8448u; RD2(pr##S, a##S) }
#define TSLOT(S, W) { LGW(W) CONSUME(pr##S) }
#define SCAN_PRO()                                                                     \
    uint32_t a0 = spB, a1 = spB+1056u, a2 = spB+2112u, a3 = spB+3168u,                 \
             a4 = spB+4224u, a5 = spB+5280u, a6 = spB+6336u, a7 = spB+7392u;           \
    f32x2 pr0, pr1, pr2, pr3, pr4, pr5, pr6, pr7;                                      \
    RD2(pr0,a0) RD2(pr1,a1) RD2(pr2,a2) RD2(pr3,a3)                                    \
    RD2(pr4,a4) RD2(pr5,a5) RD2(pr6,a6) RD2(pr7,a7)
#define SCAN_TAIL8()                                                                   \
    TSLOT(0,7) TSLOT(1,6) TSLOT(2,5) TSLOT(3,4)                                        \
    TSLOT(4,3) TSLOT(5,2) TSLOT(6,1) TSLOT(7,0)

  // ================= main phase loop =================
  if (wid < 2) STAGE(0, 0);

#pragma unroll 1
  for (int ph = 0; ph <= NCH; ++ph) {
    if (wid < 2) {
      // ------- producer phase: GEMM chunk ph, stage chunk ph+1 -------
      if (ph <= NCH - 1) {
        asm volatile("s_waitcnt vmcnt(0)" ::: "memory");   // own staging for chunk ph
        if (ph < NCH - 1) STAGE(ph + 1, (ph + 1) & 1);
        const int pbuf = ph & 1;
        if (ph < NCH - 1) {
          GEMM_MT(0)
          GEMM_MT(1)
        } else if (wid == 0) {     // tail: 16 steps = MT0 only
          GEMM_MT(0)
        }
        asm volatile("s_waitcnt lgkmcnt(0)" ::: "memory"); // cur writes complete
      }
    } else {
      // ------- scanner phase: scan chunk ph-1 -------
      if (ph >= 1) {
        const uint32_t spB = curB + (uint32_t)(((ph - 1) & 1) * 33792 + 4 * (sid * 64 + l));
        if (ph - 1 < NCH - 1) {
          SCAN_PRO()
          SSLOT(0) SSLOT(1) SSLOT(2) SSLOT(3) SSLOT(4) SSLOT(5) SSLOT(6) SSLOT(7)
          SSLOT(0) SSLOT(1) SSLOT(2) SSLOT(3) SSLOT(4) SSLOT(5) SSLOT(6) SSLOT(7)
          SSLOT(0) SSLOT(1) SSLOT(2) SSLOT(3) SSLOT(4) SSLOT(5) SSLOT(6) SSLOT(7)
          SCAN_TAIL8()
        } else {                   // tail chunk: 16 steps = 8 pairs
          SCAN_PRO()
          SCAN_TAIL8()
        }
        if (ph == NCH) cnt_s[sid * 64 + l] = (float)cnt;
      }
    }
    __syncthreads();
  }

  // ---- fused epilogue: logits from spike counts ----
  if (tid < Cdim) {
    float dot = 0.0f;
#pragma unroll
    for (int k = 0; k < Hdim; ++k)
      dot = fmaf(cnt_s[k], W2[tid * Hdim + k], dot);
    const float Tf = (float)Tdim;
    const float scale = 1.0f / Tf + 0.1f / (Tf + 1e-6f);
    out[b * Cdim + tid] = fmaf(dot, scale, 1.1f * b2[tid]);
  }
}

extern "C" void kernel_launch(void* const* d_in, const int* in_sizes, int n_in,
                              void* d_out, int out_size, void* d_ws, size_t ws_size,
                              hipStream_t stream) {
  const float* x  = (const float*)d_in[0];
  const float* W1 = (const float*)d_in[1];
  const float* b1 = (const float*)d_in[2];
  const float* W2 = (const float*)d_in[3];
  const float* b2 = (const float*)d_in[4];
  float* out = (float*)d_out;

  snn_spec_kernel<<<dim3(Bdim), dim3(256), 0, stream>>>(x, W1, b1, W2, b2, out);
}